// Round 1
// 2095.982 us; speedup vs baseline: 1.2002x; 1.2002x over previous
//
#include <hip/hip_runtime.h>
#include <stdint.h>

// ---------------- problem constants ----------------
#define NNODE  50000
#define FIN    2000
#define FIN_P  2048      // K padded to 2048 (zero-filled)
#define HEADS  4
#define HID    512
#define C1     2048      // HEADS*HID
#define LAT    30
#define NEDGE  800000
#define NVIRT  850000    // NEDGE + NNODE self loops
#define NEG_SLOPE 0.2f
#define BN_EPS 1e-5f

typedef __bf16 bf16x8 __attribute__((ext_vector_type(8)));
typedef float  f32x4  __attribute__((ext_vector_type(4)));

// ---------------- async global->LDS 16B ----------------
__device__ __forceinline__ void cp16(const void* g, void* l) {
  __builtin_amdgcn_global_load_lds(
      (const __attribute__((address_space(1))) unsigned int*)g,
      (__attribute__((address_space(3))) unsigned int*)l, 16, 0, 0);
}

// ---------------- dtype detection ----------------
__global__ void detect_dtype(const unsigned int* __restrict__ xw, int* __restrict__ flag) {
  __shared__ int red[256];
  const int t = threadIdx.x;
  int cnt = 0;
  for (int i = t; i < 4096; i += 256) {
    unsigned int ex = (xw[i] >> 7) & 0xFFu;
    cnt += (ex >= 115u && ex <= 130u) ? 1 : 0;
  }
  red[t] = cnt;
  __syncthreads();
  for (int s = 128; s > 0; s >>= 1) {
    if (t < s) red[t] += red[t + s];
    __syncthreads();
  }
  if (t == 0) *flag = (red[0] > 2048) ? 1 : 0;  // 1 = bf16 inputs, 0 = fp32 inputs
}

// ---------------- x -> canonical bf16, K padded to 2048 ----------------
// Source rows are 2000 elements (vec8-divisible, chunks never cross rows).
// Source is read linearly (16B-aligned always); dst is row*2048 + col.
__global__ __launch_bounds__(256) void convert_x(const void* __restrict__ xin,
                                                 const int* __restrict__ flag,
                                                 __bf16* __restrict__ xb) {
  const bool isbf = (*flag != 0);
  const int NDATA = NNODE * (FIN / 8);       // 12,500,000 data chunks
  const int NPAD  = NNODE * ((FIN_P - FIN) / 8); // 300,000 pad chunks
  const int stride = gridDim.x * 256;
  for (int q = blockIdx.x * 256 + threadIdx.x; q < NDATA + NPAD; q += stride) {
    if (q < NDATA) {
      const int row = q / 250;
      const int c8  = q - row * 250;
      __bf16* dst = xb + (size_t)row * FIN_P + c8 * 8;
      const size_t si = (size_t)q * 8;
      if (isbf) {
        *(bf16x8*)dst = *(const bf16x8*)((const __bf16*)xin + si);
      } else {
        const float4 a = *(const float4*)((const float*)xin + si);
        const float4 b = *(const float4*)((const float*)xin + si + 4);
        bf16x8 o;
        o[0] = (__bf16)a.x; o[1] = (__bf16)a.y; o[2] = (__bf16)a.z; o[3] = (__bf16)a.w;
        o[4] = (__bf16)b.x; o[5] = (__bf16)b.y; o[6] = (__bf16)b.z; o[7] = (__bf16)b.w;
        *(bf16x8*)dst = o;
      }
    } else {
      const int p = q - NDATA;
      const int row = p / 6;
      const int c8  = p - row * 6;
      bf16x8 z;
#pragma unroll
      for (int j = 0; j < 8; ++j) z[j] = (__bf16)0.0f;
      *(bf16x8*)(xb + (size_t)row * FIN_P + FIN + c8 * 8) = z;
    }
  }
}

// ---------------- small param arrays -> canonical fp32 ----------------
__global__ void cvt_f32(const void* __restrict__ src, const int* __restrict__ flag,
                        float* __restrict__ dst, int n) {
  int i = blockIdx.x * 256 + threadIdx.x;
  if (i < n) dst[i] = (*flag != 0) ? (float)((const __bf16*)src)[i] : ((const float*)src)[i];
}

// ---------------- W1 [2000,2048] -> W1T [2048,2048] bf16 (k zero-padded) -----
__global__ void transpose_w1(const void* __restrict__ W1v, const int* __restrict__ flag,
                             __bf16* __restrict__ W1T) {
  __shared__ __bf16 tile[32][33];
  const bool isbf = (*flag != 0);
  const int n0 = blockIdx.x * 32, k0 = blockIdx.y * 32;
  const int tx = threadIdx.x, ty = threadIdx.y; // (32,8)
#pragma unroll
  for (int i = 0; i < 4; ++i) {
    int k = k0 + ty + i * 8;
    __bf16 v = (__bf16)0.0f;
    if (k < FIN) {
      size_t idx = (size_t)k * C1 + n0 + tx;
      v = isbf ? ((const __bf16*)W1v)[idx] : (__bf16)((const float*)W1v)[idx];
    }
    tile[ty + i * 8][tx] = v;
  }
  __syncthreads();
#pragma unroll
  for (int i = 0; i < 4; ++i) {
    int k = k0 + tx;
    int n = n0 + ty + i * 8;
    W1T[(size_t)n * FIN_P + k] = tile[tx][ty + i * 8];
  }
}

// ---------------- GEMM1: h = x @ W1 ----------------
// 256x256 tile, BK=64, 8 waves (2M x 4N), double-buffered 128 KiB LDS,
// 4-phase interleave per K-tile, counted vmcnt(2), setprio around MFMA,
// (row&7)<<4 XOR swizzle (applied to global source, inverse on ds_read),
// bijective XCD swizzle with N-tile fastest for A-panel L2 residency.
#define BM 256
#define BN 256
#define BK 64
__global__ __launch_bounds__(512, 2) void gemm1(const __bf16* __restrict__ A,
                                                const __bf16* __restrict__ BT,
                                                __bf16* __restrict__ C) {
  __shared__ __align__(128) __bf16 lds[2 * 2 * BM * BK]; // 131072 B
  const int t = threadIdx.x;
  const int lane = t & 63;
  const int wid = t >> 6;
  const int wm = wid >> 2, wn = wid & 3;
  const int quad = lane >> 4, l16 = lane & 15;

  // ---- block swizzle: XCD-bijective, ntile fastest ----
  const int nwg = gridDim.x;           // 1568, %8 == 0
  const int per = nwg >> 3;            // 196
  const int wg  = blockIdx.x;
  const int wgs = (wg & 7) * per + (wg >> 3);
  const int mtile = wgs >> 3;          // 0..195
  const int ntile = wgs & 7;           // 0..7
  const int mBase = mtile * BM, nBase = ntile * BN;

  // ---- staging geometry (per-thread, 2 chunks of 16B per half-tile) ----
  const int c0 = t, c1 = t + 512;           // chunk ids within a 1024-chunk half
  const int r0 = c0 >> 3, r1 = c1 >> 3;     // local row 0..127
  // stored-at-linear chunk holds logical column (slot ^ (row&7)); element offset:
  const int gc0 = (((c0 & 7) ^ (r0 & 7)) << 3);
  const int gc1 = (((c1 & 7) ^ (r1 & 7)) << 3);

  __bf16* const ldsE = lds;
  auto stageA = [&](int bufi, int h, int kt) {
    const int row0 = mBase + h * 128;
    int ra = row0 + r0; if (ra > NNODE - 1) ra = NNODE - 1;
    int rb = row0 + r1; if (rb > NNODE - 1) rb = NNODE - 1;
    __bf16* ld0 = ldsE + bufi * 32768 + h * 8192;
    cp16(A + (size_t)ra * FIN_P + kt * 64 + gc0, ld0 + c0 * 8);
    cp16(A + (size_t)rb * FIN_P + kt * 64 + gc1, ld0 + c1 * 8);
  };
  auto stageB = [&](int bufi, int h, int kt) {
    const int row0 = nBase + h * 128;
    __bf16* ld0 = ldsE + bufi * 32768 + 16384 + h * 8192;
    cp16(BT + (size_t)(row0 + r0) * FIN_P + kt * 64 + gc0, ld0 + c0 * 8);
    cp16(BT + (size_t)(row0 + r1) * FIN_P + kt * 64 + gc1, ld0 + c1 * 8);
  };

  // ---- fragment read addressing (bytes) ----
  const char* ldsc = (const char*)lds;
  const int swz = (l16 & 7) << 4;                  // per-lane constant (row bits 0-2 = l16)
  const int aRowByte = (wm * 128 + l16) * 128;     // + g*2048
  const int bRowByte = (wn * 64 + l16) * 128;      // + n*2048
  const int kq0 = (quad * 16) ^ swz;               // kh = 0
  const int kq1 = (64 + quad * 16) ^ swz;          // kh = 1

  f32x4 acc[8][4];
#pragma unroll
  for (int i = 0; i < 8; ++i)
#pragma unroll
    for (int j = 0; j < 4; ++j) acc[i][j] = 0;

  // ---- prologue: stage K-tile 0 into buf 0 ----
  stageA(0, 0, 0); stageA(0, 1, 0); stageB(0, 0, 0); stageB(0, 1, 0);

  const int NT = FIN_P / BK; // 32
  int buf = 0;
  for (int kt = 0; kt < NT; ++kt) {
    const int ktn = (kt < NT - 1) ? kt + 1 : 0;   // dummy re-stage keeps vmcnt counts uniform
    const int bn = buf ^ 1;
    const size_t bufA = (size_t)buf * 65536;
    const size_t bufB = bufA + 32768;

    // ===== phase 0: stage A-h0(next), gate tile kt, read B frags + A g0,g1 =====
    stageA(bn, 0, ktn);
    asm volatile("s_waitcnt vmcnt(2)" ::: "memory");
    __builtin_amdgcn_s_barrier();
    bf16x8 bf_[4][2];
#pragma unroll
    for (int n = 0; n < 4; ++n) {
      bf_[n][0] = *(const bf16x8*)(ldsc + bufB + bRowByte + n * 2048 + kq0);
      bf_[n][1] = *(const bf16x8*)(ldsc + bufB + bRowByte + n * 2048 + kq1);
    }
    bf16x8 a00 = *(const bf16x8*)(ldsc + bufA + aRowByte + 0 * 2048 + kq0);
    bf16x8 a01 = *(const bf16x8*)(ldsc + bufA + aRowByte + 0 * 2048 + kq1);
    bf16x8 a10 = *(const bf16x8*)(ldsc + bufA + aRowByte + 1 * 2048 + kq0);
    bf16x8 a11 = *(const bf16x8*)(ldsc + bufA + aRowByte + 1 * 2048 + kq1);
    __builtin_amdgcn_s_setprio(1);
#pragma unroll
    for (int n = 0; n < 4; ++n) {
      acc[0][n] = __builtin_amdgcn_mfma_f32_16x16x32_bf16(a00, bf_[n][0], acc[0][n], 0, 0, 0);
      acc[0][n] = __builtin_amdgcn_mfma_f32_16x16x32_bf16(a01, bf_[n][1], acc[0][n], 0, 0, 0);
      acc[1][n] = __builtin_amdgcn_mfma_f32_16x16x32_bf16(a10, bf_[n][0], acc[1][n], 0, 0, 0);
      acc[1][n] = __builtin_amdgcn_mfma_f32_16x16x32_bf16(a11, bf_[n][1], acc[1][n], 0, 0, 0);
    }
    __builtin_amdgcn_s_setprio(0);
    __builtin_amdgcn_s_barrier();

    // ===== phase 1: read A g2,g3; stage A-h1(next) =====
    a00 = *(const bf16x8*)(ldsc + bufA + aRowByte + 2 * 2048 + kq0);
    a01 = *(const bf16x8*)(ldsc + bufA + aRowByte + 2 * 2048 + kq1);
    a10 = *(const bf16x8*)(ldsc + bufA + aRowByte + 3 * 2048 + kq0);
    a11 = *(const bf16x8*)(ldsc + bufA + aRowByte + 3 * 2048 + kq1);
    stageA(bn, 1, ktn);
    __builtin_amdgcn_s_barrier();
    __builtin_amdgcn_s_setprio(1);
#pragma unroll
    for (int n = 0; n < 4; ++n) {
      acc[2][n] = __builtin_amdgcn_mfma_f32_16x16x32_bf16(a00, bf_[n][0], acc[2][n], 0, 0, 0);
      acc[2][n] = __builtin_amdgcn_mfma_f32_16x16x32_bf16(a01, bf_[n][1], acc[2][n], 0, 0, 0);
      acc[3][n] = __builtin_amdgcn_mfma_f32_16x16x32_bf16(a10, bf_[n][0], acc[3][n], 0, 0, 0);
      acc[3][n] = __builtin_amdgcn_mfma_f32_16x16x32_bf16(a11, bf_[n][1], acc[3][n], 0, 0, 0);
    }
    __builtin_amdgcn_s_setprio(0);
    __builtin_amdgcn_s_barrier();

    // ===== phase 2: read A g4,g5; stage B-h0(next) =====
    a00 = *(const bf16x8*)(ldsc + bufA + aRowByte + 4 * 2048 + kq0);
    a01 = *(const bf16x8*)(ldsc + bufA + aRowByte + 4 * 2048 + kq1);
    a10 = *(const bf16x8*)(ldsc + bufA + aRowByte + 5 * 2048 + kq0);
    a11 = *(const bf16x8*)(ldsc + bufA + aRowByte + 5 * 2048 + kq1);
    stageB(bn, 0, ktn);
    __builtin_amdgcn_s_barrier();
    __builtin_amdgcn_s_setprio(1);
#pragma unroll
    for (int n = 0; n < 4; ++n) {
      acc[4][n] = __builtin_amdgcn_mfma_f32_16x16x32_bf16(a00, bf_[n][0], acc[4][n], 0, 0, 0);
      acc[4][n] = __builtin_amdgcn_mfma_f32_16x16x32_bf16(a01, bf_[n][1], acc[4][n], 0, 0, 0);
      acc[5][n] = __builtin_amdgcn_mfma_f32_16x16x32_bf16(a10, bf_[n][0], acc[5][n], 0, 0, 0);
      acc[5][n] = __builtin_amdgcn_mfma_f32_16x16x32_bf16(a11, bf_[n][1], acc[5][n], 0, 0, 0);
    }
    __builtin_amdgcn_s_setprio(0);
    __builtin_amdgcn_s_barrier();

    // ===== phase 3: read A g6,g7; stage B-h1(next) =====
    a00 = *(const bf16x8*)(ldsc + bufA + aRowByte + 6 * 2048 + kq0);
    a01 = *(const bf16x8*)(ldsc + bufA + aRowByte + 6 * 2048 + kq1);
    a10 = *(const bf16x8*)(ldsc + bufA + aRowByte + 7 * 2048 + kq0);
    a11 = *(const bf16x8*)(ldsc + bufA + aRowByte + 7 * 2048 + kq1);
    stageB(bn, 1, ktn);
    __builtin_amdgcn_s_barrier();
    __builtin_amdgcn_s_setprio(1);
#pragma unroll
    for (int n = 0; n < 4; ++n) {
      acc[6][n] = __builtin_amdgcn_mfma_f32_16x16x32_bf16(a00, bf_[n][0], acc[6][n], 0, 0, 0);
      acc[6][n] = __builtin_amdgcn_mfma_f32_16x16x32_bf16(a01, bf_[n][1], acc[6][n], 0, 0, 0);
      acc[7][n] = __builtin_amdgcn_mfma_f32_16x16x32_bf16(a10, bf_[n][0], acc[7][n], 0, 0, 0);
      acc[7][n] = __builtin_amdgcn_mfma_f32_16x16x32_bf16(a11, bf_[n][1], acc[7][n], 0, 0, 0);
    }
    __builtin_amdgcn_s_setprio(0);
    __builtin_amdgcn_s_barrier();

    buf ^= 1;
  }

  // ---- epilogue: C/D layout col=lane&15, row=quad*4+reg ----
#pragma unroll
  for (int g = 0; g < 8; ++g) {
    const int row0 = mBase + wm * 128 + g * 16 + quad * 4;
#pragma unroll
    for (int n = 0; n < 4; ++n) {
      const int col = nBase + wn * 64 + n * 16 + l16;
#pragma unroll
      for (int r = 0; r < 4; ++r) {
        const int row = row0 + r;
        if (row < NNODE) C[(size_t)row * C1 + col] = (__bf16)acc[g][n][r];
      }
    }
  }
}

// ---------------- a_src1/a_dst1 [N,4] from h ----------------
__global__ __launch_bounds__(256) void attdots(const __bf16* __restrict__ h,
                                               const float* __restrict__ as1,
                                               const float* __restrict__ ad1,
                                               float* __restrict__ a_src,
                                               float* __restrict__ a_dst) {
  const int n = blockIdx.x, t = threadIdx.x, w = t >> 6; // wave w == head w
  bf16x8 hv = *(const bf16x8*)(h + (size_t)n * C1 + t * 8);
  float ps = 0.f, pd = 0.f;
#pragma unroll
  for (int j = 0; j < 8; ++j) {
    float hf = (float)hv[j];
    ps += hf * as1[t * 8 + j];
    pd += hf * ad1[t * 8 + j];
  }
  for (int off = 32; off > 0; off >>= 1) {
    ps += __shfl_down(ps, off);
    pd += __shfl_down(pd, off);
  }
  if ((t & 63) == 0) { a_src[n * 4 + w] = ps; a_dst[n * 4 + w] = pd; }
}

// ---------------- CSR build ----------------
__global__ void count_edges(const int* __restrict__ ei, int* __restrict__ cnt) {
  int e = blockIdx.x * 256 + threadIdx.x;
  if (e < NEDGE) atomicAdd(&cnt[ei[NEDGE + e]], 1);
}

__global__ __launch_bounds__(1024) void scan_csr(const int* __restrict__ cnt,
                                                 int* __restrict__ offs,
                                                 int* __restrict__ cursor) {
  __shared__ int sd[1024];
  __shared__ int carry;
  const int t = threadIdx.x;
  if (t == 0) { carry = 0; offs[0] = 0; }
  __syncthreads();
  for (int base = 0; base < NNODE; base += 1024) {
    int i = base + t;
    int v = (i < NNODE) ? cnt[i] : 0;
    sd[t] = v;
    __syncthreads();
    int x = v;
    for (int d = 1; d < 1024; d <<= 1) {
      int y = (t >= d) ? sd[t - d] : 0;
      __syncthreads();
      x += y; sd[t] = x;
      __syncthreads();
    }
    int c = carry;
    if (i < NNODE) { offs[i + 1] = c + x; cursor[i] = c + x - v; }
    __syncthreads();
    if (t == 1023) carry = c + x;
    __syncthreads();
  }
}

__global__ void fill_csr(const int* __restrict__ ei, int* __restrict__ cursor,
                         int* __restrict__ csr_src) {
  int e = blockIdx.x * 256 + threadIdx.x;
  if (e < NEDGE) {
    int s = ei[e], d = ei[NEDGE + e];
    int pos = atomicAdd(&cursor[d], 1);
    csr_src[pos] = s;
  }
}

// ---------------- edge softmax, layer1 ----------------
__global__ __launch_bounds__(64) void softmax1(const int* __restrict__ offs,
                                               const int* __restrict__ csr_src,
                                               const float* __restrict__ a_src,
                                               const float* __restrict__ a_dst,
                                               float* __restrict__ p1,
                                               float* __restrict__ rden1) {
  const int n = blockIdx.x, t = threadIdx.x;
  const int hl = t & 3, slot0 = t >> 2; // 16 slots x 4 heads
  const int off0 = offs[n], deg = offs[n + 1] - off0;
  const float adn = a_dst[n * 4 + hl];
  float mx = -3.4e38f;
  for (int i = slot0; i <= deg; i += 16) {
    int s = (i < deg) ? csr_src[off0 + i] : n;
    float e = a_src[s * 4 + hl] + adn;
    e = e > 0.f ? e : NEG_SLOPE * e;
    mx = fmaxf(mx, e);
  }
  for (int d = 4; d < 64; d <<= 1) mx = fmaxf(mx, __shfl_xor(mx, d));
  float sum = 0.f;
  for (int i = slot0; i <= deg; i += 16) {
    int s, pidx;
    if (i < deg) { pidx = off0 + i; s = csr_src[pidx]; }
    else         { pidx = NEDGE + n; s = n; }
    float e = a_src[s * 4 + hl] + adn;
    e = e > 0.f ? e : NEG_SLOPE * e;
    float p = __expf(e - mx);
    p1[(size_t)pidx * 4 + hl] = p;
    sum += p;
  }
  for (int d = 4; d < 64; d <<= 1) sum += __shfl_xor(sum, d);
  if (t < 4) rden1[n * 4 + t] = 1.0f / (sum + 1e-16f);
}

// ---------------- aggregate layer1 + head-mean + b1 -> h1 [N,512] fp32 ---------
__global__ __launch_bounds__(256) void aggregate1(const int* __restrict__ offs,
                                                  const int* __restrict__ csr_src,
                                                  const __bf16* __restrict__ h,
                                                  const float* __restrict__ p1,
                                                  const float* __restrict__ rden1,
                                                  const float* __restrict__ b1,
                                                  float* __restrict__ h1) {
  __shared__ float sred[256][9]; // +1 pad
  const int n = blockIdx.x, t = threadIdx.x, head = t >> 6;
  const int off0 = offs[n], deg = offs[n + 1] - off0;
  float acc[8] = {0, 0, 0, 0, 0, 0, 0, 0};
  for (int i = 0; i <= deg; ++i) {
    int s, pidx;
    if (i < deg) { pidx = off0 + i; s = csr_src[pidx]; }
    else         { pidx = NEDGE + n; s = n; }
    const float4 pv = *(const float4*)(p1 + (size_t)pidx * 4);
    float al = head == 0 ? pv.x : head == 1 ? pv.y : head == 2 ? pv.z : pv.w;
    bf16x8 hv = *(const bf16x8*)(h + (size_t)s * C1 + t * 8);
#pragma unroll
    for (int j = 0; j < 8; ++j) acc[j] += al * (float)hv[j];
  }
  const float4 rd = *(const float4*)(rden1 + n * 4);
  float r = head == 0 ? rd.x : head == 1 ? rd.y : head == 2 ? rd.z : rd.w;
#pragma unroll
  for (int j = 0; j < 8; ++j) sred[t][j] = acc[j] * r;
  __syncthreads();
  if (t < 64) {
#pragma unroll
    for (int j = 0; j < 8; ++j) {
      float v = sred[t][j] + sred[t + 64][j] + sred[t + 128][j] + sred[t + 192][j];
      h1[(size_t)n * HID + t * 8 + j] = 0.25f * v + b1[t * 8 + j];
    }
  }
}

// ---------------- BN statistics ----------------
__global__ __launch_bounds__(256) void bn_stats(const float* __restrict__ h1,
                                                float* __restrict__ sums) {
  const int t = threadIdx.x;
  float s0 = 0, s1 = 0, q0 = 0, q1 = 0;
  for (int r = blockIdx.x; r < NNODE; r += gridDim.x) {
    float a = h1[(size_t)r * HID + t];
    float b = h1[(size_t)r * HID + t + 256];
    s0 += a; q0 += a * a;
    s1 += b; q1 += b * b;
  }
  atomicAdd(&sums[t], s0);
  atomicAdd(&sums[t + 256], s1);
  atomicAdd(&sums[HID + t], q0);
  atomicAdd(&sums[HID + t + 256], q1);
}

__global__ void bn_final(const float* __restrict__ sums, const float* __restrict__ gamma,
                         const float* __restrict__ beta, float* __restrict__ scale,
                         float* __restrict__ shift) {
  const int c = threadIdx.x;
  const float inv_n = 1.0f / (float)NNODE;
  float mu = sums[c] * inv_n;
  float var = sums[HID + c] * inv_n - mu * mu;
  float rstd = rsqrtf(var + BN_EPS);
  float g = gamma[c];
  scale[c] = rstd * g;
  shift[c] = beta[c] - mu * rstd * g;
}

// ---------------- BN+ELU + GEMM2 (512x30) + att2 dots ----------------
__global__ __launch_bounds__(256) void layer2(const float* __restrict__ h1,
                                              const float* __restrict__ scale,
                                              const float* __restrict__ shift,
                                              const float* __restrict__ W2,
                                              const float* __restrict__ as2w,
                                              const float* __restrict__ ad2w,
                                              float* __restrict__ z0,
                                              float* __restrict__ as2,
                                              float* __restrict__ ad2) {
  __shared__ float w2s[HID * LAT];
  __shared__ float h2s[HID];
  __shared__ float zpart[8 * LAT];
  __shared__ float red1[32], red2[32];
  __shared__ float asv[LAT], adv[LAT];
  __shared__ float scv[HID], shv[HID];
  const int t = threadIdx.x;
  for (int i = t; i < HID * LAT; i += 256) w2s[i] = W2[i];
  if (t < LAT) { asv[t] = as2w[t]; adv[t] = ad2w[t]; }
  for (int i = t; i < HID; i += 256) { scv[i] = scale[i]; shv[i] = shift[i]; }
  __syncthreads();
  const int s = t / LAT, c = t % LAT;
  const bool act = t < 240;
  for (int row = blockIdx.x; row < NNODE; row += gridDim.x) {
    for (int i = t; i < HID; i += 256) {
      float v = h1[(size_t)row * HID + i] * scv[i] + shv[i];
      h2s[i] = v > 0.f ? v : expm1f(v); // ELU
    }
    __syncthreads();
    if (act) {
      float acc = 0.f;
      const float* hp = &h2s[s * 64];
      const float* wp = &w2s[s * 64 * LAT + c];
#pragma unroll 8
      for (int k = 0; k < 64; ++k) acc += hp[k] * wp[k * LAT];
      zpart[s * LAT + c] = acc;
    }
    __syncthreads();
    if (t < LAT) {
      float z = 0.f;
#pragma unroll
      for (int ss = 0; ss < 8; ++ss) z += zpart[ss * LAT + t];
      z0[(size_t)row * LAT + t] = z;
      red1[t] = z * asv[t];
      red2[t] = z * adv[t];
    }
    __syncthreads();
    if (t == 0) {
      float a = 0.f, b = 0.f;
      for (int i = 0; i < LAT; ++i) { a += red1[i]; b += red2[i]; }
      as2[row] = a;
      ad2[row] = b;
    }
    __syncthreads();
  }
}

// ---------------- edge softmax, layer2 ----------------
__global__ __launch_bounds__(64) void softmax2(const int* __restrict__ offs,
                                               const int* __restrict__ csr_src,
                                               const float* __restrict__ as2,
                                               const float* __restrict__ ad2,
                                               float* __restrict__ p2,
                                               float* __restrict__ rden2) {
  const int n = blockIdx.x, t = threadIdx.x;
  const int off0 = offs[n], deg = offs[n + 1] - off0;
  const float adn = ad2[n];
  float mx = -3.4e38f;
  for (int i = t; i <= deg; i += 64) {
    int s = (i < deg) ? csr_src[off0 + i] : n;
    float e = as2[s] + adn;
    e = e > 0.f ? e : NEG_SLOPE * e;
    mx = fmaxf(mx, e);
  }
  for (int d = 1; d < 64; d <<= 1) mx = fmaxf(mx, __shfl_xor(mx, d));
  float sum = 0.f;
  for (int i = t; i <= deg; i += 64) {
    int s, pidx;
    if (i < deg) { pidx = off0 + i; s = csr_src[pidx]; }
    else         { pidx = NEDGE + n; s = n; }
    float e = as2[s] + adn;
    e = e > 0.f ? e : NEG_SLOPE * e;
    float p = __expf(e - mx);
    p2[pidx] = p;
    sum += p;
  }
  for (int d = 1; d < 64; d <<= 1) sum += __shfl_xor(sum, d);
  if (t == 0) rden2[n] = 1.0f / (sum + 1e-16f);
}

// ---------------- aggregate layer2 -> out (dtype per flag) ----------------
__global__ __launch_bounds__(64) void aggregate2(const int* __restrict__ offs,
                                                 const int* __restrict__ csr_src,
                                                 const float* __restrict__ z0,
                                                 const float* __restrict__ p2,
                                                 const float* __restrict__ rden2,
                                                 const float* __restrict__ b2,
                                                 const int* __restrict__ flag,
                                                 void* __restrict__ out) {
  const int n = blockIdx.x, t = threadIdx.x;
  const int off0 = offs[n], deg = offs[n + 1] - off0;
  float acc = 0.f;
  for (int i = 0; i <= deg; ++i) {
    int s, pidx;
    if (i < deg) { pidx = off0 + i; s = csr_src[pidx]; }
    else         { pidx = NEDGE + n; s = n; }
    float p = p2[pidx];
    if (t < LAT) acc += p * z0[(size_t)s * LAT + t];
  }
  if (t < LAT) {
    float v = acc * rden2[n] + b2[t];
    size_t idx = (size_t)n * LAT + t;
    if (*flag != 0) ((__bf16*)out)[idx] = (__bf16)v;
    else            ((float*)out)[idx]  = v;
  }
}

// ---------------- host launch ----------------
extern "C" void kernel_launch(void* const* d_in, const int* in_sizes, int n_in,
                              void* d_out, int out_size, void* d_ws, size_t ws_size,
                              hipStream_t stream) {
  const void* x_raw   = d_in[0];
  const int*  ei      = (const int*)d_in[1];
  const void* W1_raw  = d_in[2];
  const void* as1_raw = d_in[3];
  const void* ad1_raw = d_in[4];
  const void* b1_raw  = d_in[5];
  const void* gam_raw = d_in[6];
  const void* bet_raw = d_in[7];
  const void* W2_raw  = d_in[8];
  const void* as2_raw = d_in[9];
  const void* ad2_raw = d_in[10];
  const void* b2_raw  = d_in[11];

  char* ws = (char*)d_ws;
  size_t o = 0;
  auto take = [&](size_t bytes) -> char* {
    char* p = ws + o;
    o += (bytes + 255) & ~(size_t)255;
    return p;
  };
  // Arena A: xb (204.8 MB, K padded), later aliased by h1 (102.4 MB) + z0 (6 MB)
  char*   arenaA  = take((size_t)NNODE * FIN_P * 2);
  __bf16* xb      = (__bf16*)arenaA;
  float*  h1      = (float*)arenaA;                          // alias (post-gemm1)
  float*  z0      = (float*)(arenaA + 102400512);            // alias, after h1
  // Arena B: w1t (8.39 MB, K padded), later aliased by p2/rden2/as2v/ad2v
  char*   arenaB  = take((size_t)C1 * FIN_P * 2);
  __bf16* w1t     = (__bf16*)arenaB;
  float*  p2      = (float*)arenaB;                          // 3.4 MB
  float*  rden2   = (float*)(arenaB + 3400192);
  float*  as2v    = (float*)(arenaB + 3600384);
  float*  ad2v    = (float*)(arenaB + 3800576);
  // Persistent
  __bf16* h       = (__bf16*)take((size_t)NNODE * C1 * 2);   // 204.8 MB
  float*  a_src1  = (float*)take((size_t)NNODE * 4 * 4);
  float*  a_dst1  = (float*)take((size_t)NNODE * 4 * 4);
  int*    cnt     = (int*)take((size_t)NNODE * 4);
  int*    offs    = (int*)take((size_t)(NNODE + 1) * 4);
  int*    cursor  = (int*)take((size_t)NNODE * 4);
  int*    csr_src = (int*)take((size_t)NEDGE * 4);
  float*  p1      = (float*)take((size_t)NVIRT * 4 * 4);     // 13.6 MB
  float*  rden1   = (float*)take((size_t)NNODE * 4 * 4);
  float*  bn_sums = (float*)take((size_t)2 * HID * 4);
  float*  bn_sc   = (float*)take((size_t)HID * 4);
  float*  bn_sh   = (float*)take((size_t)HID * 4);
  float*  as1f    = (float*)take((size_t)C1 * 4);
  float*  ad1f    = (float*)take((size_t)C1 * 4);
  float*  b1f     = (float*)take((size_t)HID * 4);
  float*  gamf    = (float*)take((size_t)HID * 4);
  float*  betf    = (float*)take((size_t)HID * 4);
  float*  W2f     = (float*)take((size_t)HID * LAT * 4);
  float*  as2f    = (float*)take((size_t)LAT * 4);
  float*  ad2f    = (float*)take((size_t)LAT * 4);
  float*  b2f     = (float*)take((size_t)LAT * 4);
  int*    flag    = (int*)take(256);
  (void)ws_size; (void)in_sizes; (void)n_in; (void)out_size;

  hipMemsetAsync(cnt, 0, (size_t)NNODE * 4, stream);
  hipMemsetAsync(bn_sums, 0, (size_t)2 * HID * 4, stream);

  // dtype detection + canonicalization
  detect_dtype<<<1, 256, 0, stream>>>((const unsigned int*)x_raw, flag);
  convert_x<<<4096, 256, 0, stream>>>(x_raw, flag, xb);
  cvt_f32<<<(C1 + 255) / 256, 256, 0, stream>>>(as1_raw, flag, as1f, C1);
  cvt_f32<<<(C1 + 255) / 256, 256, 0, stream>>>(ad1_raw, flag, ad1f, C1);
  cvt_f32<<<2, 256, 0, stream>>>(b1_raw, flag, b1f, HID);
  cvt_f32<<<2, 256, 0, stream>>>(gam_raw, flag, gamf, HID);
  cvt_f32<<<2, 256, 0, stream>>>(bet_raw, flag, betf, HID);
  cvt_f32<<<(HID * LAT + 255) / 256, 256, 0, stream>>>(W2_raw, flag, W2f, HID * LAT);
  cvt_f32<<<1, 256, 0, stream>>>(as2_raw, flag, as2f, LAT);
  cvt_f32<<<1, 256, 0, stream>>>(ad2_raw, flag, ad2f, LAT);
  cvt_f32<<<1, 256, 0, stream>>>(b2_raw, flag, b2f, LAT);

  // CSR build
  count_edges<<<(NEDGE + 255) / 256, 256, 0, stream>>>(ei, cnt);
  scan_csr<<<1, 1024, 0, stream>>>(cnt, offs, cursor);
  fill_csr<<<(NEDGE + 255) / 256, 256, 0, stream>>>(ei, cursor, csr_src);

  // layer 1
  transpose_w1<<<dim3(C1 / 32, FIN_P / 32), dim3(32, 8), 0, stream>>>(W1_raw, flag, w1t);
  gemm1<<<dim3(((NNODE + 255) / 256) * (C1 / 256)), 512, 0, stream>>>(xb, w1t, h);
  attdots<<<NNODE, 256, 0, stream>>>(h, as1f, ad1f, a_src1, a_dst1);
  softmax1<<<NNODE, 64, 0, stream>>>(offs, csr_src, a_src1, a_dst1, p1, rden1);
  aggregate1<<<NNODE, 256, 0, stream>>>(offs, csr_src, h, p1, rden1, b1f, h1);

  // batchnorm
  bn_stats<<<512, 256, 0, stream>>>(h1, bn_sums);
  bn_final<<<1, HID, 0, stream>>>(bn_sums, gamf, betf, bn_sc, bn_sh);

  // layer 2
  layer2<<<1024, 256, 0, stream>>>(h1, bn_sc, bn_sh, W2f, as2f, ad2f, z0, as2v, ad2v);
  softmax2<<<NNODE, 64, 0, stream>>>(offs, csr_src, as2v, ad2v, p2, rden2);
  aggregate2<<<NNODE, 64, 0, stream>>>(offs, csr_src, z0, p2, rden2, b2f, flag, (void*)d_out);
}